// Round 6
// baseline (191.466 us; speedup 1.0000x reference)
//
#include <hip/hip_runtime.h>

// Problem constants (from reference):
//   L=36, G=180, A=0.2, RO=2.5, RMAX=13, B=27, CELLS=27^3=19683
//   NRAD=8, NL=4 -> 16 masked (l,m) pairs, VCELL=0.008
#define G 180
#define NRAD 8
#define RO_F 2.5f
#define A_F 0.2f
#define VCELL_F 0.008f
#define CELLS 19683
#define SLABS 16
#define NATOMS 64
#define ITERS 10          // ceil(19683 / (SLABS*128)); padded cells have R>RO
#define MAGIC 0x1ACEB00Cu

// Single-dispatch stream-k design (R5 post-mortem: ~5-10us/dispatch graph
// overhead dominates the controllable window; kernel body is ~5us):
//   wave w: radial group g=w>>1 (radials 4g..4g+3), cell subgroup cw=w&1
//   -> acc[64]/thread, 2x geometry redundancy, 128 distinct cells/block/iter.
//   Tail: init-robust magic-flag protocol (R3's atomicInc-wrap was only
//   self-resetting from poison >= wrap; flags+reset work from ANY init).
//
// ws layout:
//   float partials[NATOMS][SLABS][4][64]           (1 MB, fully overwritten)
//   unsigned flags[NATOMS][SLABS] at FLAG_OFF      (MAGIC protocol, reset to
//                                                   0 by finalizer each call)
#define FLAG_OFF (NATOMS * SLABS * 4 * 64)

// lm ordering (matches coeff[:, MASK].reshape(-1)):
// 0:(0,0) 1:(1,-1) 2:(1,0) 3:(1,1) 4:(2,-2) 5:(2,-1) 6:(2,0) 7:(2,1) 8:(2,2)
// 9:(3,-3) 10:(3,-2) 11:(3,-1) 12:(3,0) 13:(3,1) 14:(3,2) 15:(3,3)

__global__ __launch_bounds__(256, 2) void proj_fused_kernel(
    const float* __restrict__ rho, const float* __restrict__ pos,
    const float* __restrict__ W, float* __restrict__ out,
    float* __restrict__ ws)
{
    const int atom = blockIdx.y;
    const int slab = blockIdx.x;
    const int tid  = threadIdx.x;
    const int lane = tid & 63;
    const int w    = tid >> 6;
    const int g    = w >> 1;          // radial group: n = 4g..4g+3
    const int cw   = w & 1;           // cell subgroup

    const float px = pos[atom*3+0], py = pos[atom*3+1], pz = pos[atom*3+2];
    // cm = round(pos/A); dr = pos - A*cm   (A = 0.2 -> pos*5)
    const float cmx = rintf(px * 5.0f), cmy = rintf(py * 5.0f), cmz = rintf(pz * 5.0f);
    const float drx = px - A_F*cmx, dry = py - A_F*cmy, drz = pz - A_F*cmz;
    const int icx = (int)cmx - 13, icy = (int)cmy - 13, icz = (int)cmz - 13;

    float acc[64];
    #pragma unroll
    for (int j = 0; j < 64; ++j) acc[j] = 0.0f;

    int c = slab*128 + cw*64 + lane;

    // prefetch cell 0
    int i_n, j_n, k_n; float s_n;
    {
        int i = c / 729; int rem = c - i*729; int j = rem / 27; int k = rem - j*27;
        int gx = i + icx; gx += (gx < 0) ? G : 0; gx -= (gx >= G) ? G : 0;
        int gy = j + icy; gy += (gy < 0) ? G : 0; gy -= (gy >= G) ? G : 0;
        int gz = k + icz; gz += (gz < 0) ? G : 0; gz -= (gz >= G) ? G : 0;
        i_n = i; j_n = j; k_n = k;
        s_n = rho[(gx*G + gy)*G + gz];
    }

    for (int it = 0; it < ITERS; ++it) {
        const int i = i_n, j = j_n, k = k_n;
        const float s = s_n;
        c += SLABS*128;
        if (it != ITERS-1) {        // prefetch next cell (overlaps compute)
            int i2 = c / 729; int rem = c - i2*729; int j2 = rem / 27; int k2 = rem - j2*27;
            int gx = i2 + icx; gx += (gx < 0) ? G : 0; gx -= (gx >= G) ? G : 0;
            int gy = j2 + icy; gy += (gy < 0) ? G : 0; gy -= (gy >= G) ? G : 0;
            int gz = k2 + icz; gz += (gz < 0) ? G : 0; gz -= (gz >= G) ? G : 0;
            i_n = i2; j_n = j2; k_n = k2;
            s_n = rho[(gx*G + gy)*G + gz];
        }

        float x = (float)(i-13)*A_F - drx;
        float y = (float)(j-13)*A_F - dry;
        float z = (float)(k-13)*A_F - drz;
        float r2 = x*x + y*y + z*z;
        float inv = rsqrtf(fmaxf(r2, 1e-24f));
        float R = r2 * inv;                 // == sqrt(r2)
        if (R < RO_F) {
            float t = RO_F - R;
            float ux = x*inv, uy = y*inv, uz = z*inv;
            float uz2 = uz*uz;
            float ux2 = ux*ux, uy2 = uy*uy;
            float ys[16];
            ys[0]  = 0.28209479177f;
            ys[1]  = 0.48860251190f * uy;
            ys[2]  = 0.48860251190f * uz;
            ys[3]  = 0.48860251190f * ux;
            ys[4]  = 1.09254843059f * ux*uy;            // 2 * 0.54627 * ux uy
            ys[5]  = 1.09254843059f * uy*uz;
            ys[6]  = 0.31539156525f * (3.0f*uz2 - 1.0f);
            ys[7]  = 1.09254843059f * ux*uz;
            ys[8]  = 0.54627421530f * (ux2 - uy2);
            ys[9]  = 0.59004358993f * uy*(3.0f*ux2 - uy2);
            ys[10] = 2.89061144264f * ux*uy*uz;         // 2 * 1.44530572
            ys[11] = 0.45704579946f * uy*(5.0f*uz2 - 1.0f);
            ys[12] = 0.37317633259f * uz*(5.0f*uz2 - 3.0f);
            ys[13] = 0.45704579946f * ux*(5.0f*uz2 - 1.0f);
            ys[14] = 1.44530572132f * (ux2 - uy2)*uz;
            ys[15] = 0.59004358993f * ux*(ux2 - 3.0f*uy2);

            // group's first radial: p0 = s * r2 * t^(2+4g)   (g wave-uniform)
            float t2 = t*t;
            float p0 = s * r2 * t2;
            if (g) { float t4 = t2*t2; p0 *= t4; }
            float p1 = p0*t, p2 = p1*t, p3 = p2*t;
            #pragma unroll
            for (int q = 0; q < 16; ++q) {
                acc[q]    = fmaf(p0, ys[q], acc[q]);
                acc[16+q] = fmaf(p1, ys[q], acc[16+q]);
                acc[32+q] = fmaf(p2, ys[q], acc[32+q]);
                acc[48+q] = fmaf(p3, ys[q], acc[48+q]);
            }
        }
    }

    // Wave-local reduction (each wave owns red[w] -> no barriers).
    // Pad-33 transpose: both phases are 2-way bank aliases = free (m136).
    __shared__ float red[4][64][33];      // ~33.8 KB
    const int col  = lane & 31;
    const int half = lane >> 5;
    #pragma unroll
    for (int ch = 0; ch < 2; ++ch) {
        #pragma unroll
        for (int q = 0; q < 32; ++q)
            red[w][lane][q] = acc[ch*32 + q];
        float csum = 0.0f;
        #pragma unroll
        for (int r = 0; r < 32; ++r)
            csum += red[w][half*32 + r][col];
        float other = __shfl_down(csum, 32);   // half 1 -> half 0
        if (lane < 32)
            ws[((atom*SLABS + slab)*4 + w)*64 + ch*32 + lane] = csum + other;
    }

    // --- stream-k tail: magic-flag protocol (init-robust) ---
    unsigned* flags = (unsigned*)(ws + FLAG_OFF);
    __threadfence();                  // release: partials device-visible
    __syncthreads();                  // all lanes' stores+fences done
    if (tid == 0)
        atomicExch(&flags[atom*SLABS + slab], MAGIC);

    if (slab == 0) {
        if (tid < SLABS) {
            while (__hip_atomic_load(&flags[atom*SLABS + tid],
                                     __ATOMIC_RELAXED,
                                     __HIP_MEMORY_SCOPE_AGENT) != MAGIC) {}
        }
        __syncthreads();
        __threadfence();              // acquire: see all producers' partials
        if (tid < 128) {
            const int n = tid >> 4, q = tid & 15;
            const int gg = n >> 2, r = n & 3;
            const float* base = ws + atom*SLABS*4*64;
            float m = 0.0f;
            #pragma unroll
            for (int s = 0; s < SLABS; ++s) {
                m += base[(s*4 + gg*2 + 0)*64 + r*16 + q];
                m += base[(s*4 + gg*2 + 1)*64 + r*16 + q];
            }
            __shared__ float M[8][16];
            M[n][q] = m;
            __syncthreads();
            float sum = 0.0f;
            #pragma unroll
            for (int k = 0; k < 8; ++k)
                sum = fmaf(W[n*8+k], M[k][q], sum);
            out[atom*128 + tid] = sum * VCELL_F;
        } else {
            __syncthreads();          // match tail's barrier (block-uniform)
        }
        __syncthreads();
        if (tid < SLABS)              // reset so next call never sees stale MAGIC
            __hip_atomic_store(&flags[atom*SLABS + tid], 0u,
                               __ATOMIC_RELAXED, __HIP_MEMORY_SCOPE_AGENT);
    }
}

extern "C" void kernel_launch(void* const* d_in, const int* in_sizes, int n_in,
                              void* d_out, int out_size, void* d_ws, size_t ws_size,
                              hipStream_t stream) {
    const float* rho = (const float*)d_in[0];   // 180^3
    const float* pos = (const float*)d_in[1];   // 64 x 3
    const float* W   = (const float*)d_in[2];   // 8 x 8
    float* out = (float*)d_out;                 // 64 x 128 fp32
    float* ws  = (float*)d_ws;                  // partials + flags

    dim3 grid(SLABS, NATOMS);
    proj_fused_kernel<<<grid, 256, 0, stream>>>(rho, pos, W, out, ws);
}

// Round 7
// 79.065 us; speedup vs baseline: 2.4216x; 2.4216x over previous
//
#include <hip/hip_runtime.h>

// Problem constants (from reference):
//   L=36, G=180, A=0.2, RO=2.5, RMAX=13, B=27, CELLS=27^3=19683
//   NRAD=8, NL=4 -> 16 masked (l,m) pairs, VCELL=0.008
#define G 180
#define NRAD 8
#define RO_F 2.5f
#define A_F 0.2f
#define VCELL_F 0.008f
#define CELLS 19683
#define SLABS 16
#define NATOMS 64
#define ITERS 10          // ceil(19683 / (SLABS*128)); padded cells have R>RO

typedef float float2v __attribute__((ext_vector_type(2)));

// lm ordering (matches coeff[:, MASK].reshape(-1)):
// 0:(0,0) 1:(1,-1) 2:(1,0) 3:(1,1) 4:(2,-2) 5:(2,-1) 6:(2,0) 7:(2,1) 8:(2,2)
// 9:(3,-3) 10:(3,-2) 11:(3,-1) 12:(3,0) 13:(3,1) 14:(3,2) 15:(3,3)
//
// R6 post-mortem: fused tails (atomics/spin/fence in-kernel) collapse the
// register allocator (VGPR 60 < acc count -> scratch spill, 132us). Stay
// with the proven 2-kernel structure; attack proj's VALU count instead:
//   * packed fp32: acc as 32 x float2, 32 v_pk_fma_f32 per cell instead of
//     64 scalar FMA (CDNA4 fp32 peak requires pk)
//   * incremental (i,j,k) decode: step 2048 = (+2, +21, +23) in base
//     (729, 27) with carries -- no integer divides in the loop
// Decomposition unchanged from R5: wave w -> radial group g=w>>1 (radials
// 4g..4g+3), cell subgroup cw=w&1; acc 64 floats/thread; 128 distinct
// cells/block/iter; rho prefetch one iteration ahead.
//
// ws layout: float partials[NATOMS][SLABS][4][64] (1 MB, fully overwritten
// every call -> no zero-init, safe vs 0xAA poison).

__global__ __launch_bounds__(256, 3) void proj_kernel(
    const float* __restrict__ rho, const float* __restrict__ pos,
    float* __restrict__ ws)
{
    const int atom = blockIdx.y;
    const int slab = blockIdx.x;
    const int tid  = threadIdx.x;
    const int lane = tid & 63;
    const int w    = tid >> 6;
    const int g    = w >> 1;          // radial group: n = 4g..4g+3
    const int cw   = w & 1;           // cell subgroup

    const float px = pos[atom*3+0], py = pos[atom*3+1], pz = pos[atom*3+2];
    // cm = round(pos/A); dr = pos - A*cm   (A = 0.2 -> pos*5)
    const float cmx = rintf(px * 5.0f), cmy = rintf(py * 5.0f), cmz = rintf(pz * 5.0f);
    const float drx = px - A_F*cmx, dry = py - A_F*cmy, drz = pz - A_F*cmz;
    const int icx = (int)cmx - 13, icy = (int)cmy - 13, icz = (int)cmz - 13;

    float2v acc2[32];                 // acc2[l>>1][l&1], l = r*16+q (r=n-4g)
    #pragma unroll
    for (int j = 0; j < 32; ++j) acc2[j] = (float2v){0.0f, 0.0f};

    // decode cell 0 (the only integer divides in the kernel)
    const int c0 = slab*128 + cw*64 + lane;
    int i_n = c0 / 729;
    int rem = c0 - i_n*729;
    int j_n = rem / 27;
    int k_n = rem - j_n*27;

    // prefetch cell 0
    float s_n;
    {
        int gx = i_n + icx; gx += (gx < 0) ? G : 0; gx -= (gx >= G) ? G : 0;
        int gy = j_n + icy; gy += (gy < 0) ? G : 0; gy -= (gy >= G) ? G : 0;
        int gz = k_n + icz; gz += (gz < 0) ? G : 0; gz -= (gz >= G) ? G : 0;
        s_n = rho[(gx*G + gy)*G + gz];
    }

    for (int it = 0; it < ITERS; ++it) {
        const int i = i_n, j = j_n, k = k_n;
        const float s = s_n;
        if (it != ITERS-1) {        // prefetch next cell (overlaps compute)
            // linear step +2048 = +2*729 + 21*27 + 23, with carries
            int kk = k_n + 23, jc = 0;
            if (kk >= 27) { kk -= 27; jc = 1; }
            int jj = j_n + 21 + jc, ic = 0;
            if (jj >= 27) { jj -= 27; ic = 1; }
            int ii = i_n + 2 + ic;
            i_n = ii; j_n = jj; k_n = kk;
            int gx = ii + icx; gx += (gx < 0) ? G : 0; gx -= (gx >= G) ? G : 0;
            int gy = jj + icy; gy += (gy < 0) ? G : 0; gy -= (gy >= G) ? G : 0;
            int gz = kk + icz; gz += (gz < 0) ? G : 0; gz -= (gz >= G) ? G : 0;
            s_n = rho[(gx*G + gy)*G + gz];
        }

        float x = (float)(i-13)*A_F - drx;
        float y = (float)(j-13)*A_F - dry;
        float z = (float)(k-13)*A_F - drz;
        float r2 = x*x + y*y + z*z;
        float inv = rsqrtf(fmaxf(r2, 1e-24f));
        float R = r2 * inv;                 // == sqrt(r2)
        if (R < RO_F) {
            float t = RO_F - R;
            float ux = x*inv, uy = y*inv, uz = z*inv;
            float uz2 = uz*uz;
            float ux2 = ux*ux, uy2 = uy*uy;
            float2v ys2[8];
            ys2[0] = (float2v){0.28209479177f,
                               0.48860251190f * uy};
            ys2[1] = (float2v){0.48860251190f * uz,
                               0.48860251190f * ux};
            ys2[2] = (float2v){1.09254843059f * ux*uy,
                               1.09254843059f * uy*uz};
            ys2[3] = (float2v){0.31539156525f * (3.0f*uz2 - 1.0f),
                               1.09254843059f * ux*uz};
            ys2[4] = (float2v){0.54627421530f * (ux2 - uy2),
                               0.59004358993f * uy*(3.0f*ux2 - uy2)};
            ys2[5] = (float2v){2.89061144264f * ux*uy*uz,
                               0.45704579946f * uy*(5.0f*uz2 - 1.0f)};
            ys2[6] = (float2v){0.37317633259f * uz*(5.0f*uz2 - 3.0f),
                               0.45704579946f * ux*(5.0f*uz2 - 1.0f)};
            ys2[7] = (float2v){1.44530572132f * (ux2 - uy2)*uz,
                               0.59004358993f * ux*(ux2 - 3.0f*uy2)};

            // group's first radial: p0 = s * r2 * t^(2+4g)   (g wave-uniform)
            float t2 = t*t;
            float p0 = s * r2 * t2;
            if (g) { float t4 = t2*t2; p0 *= t4; }
            float p1 = p0*t, p2 = p1*t, p3 = p2*t;
            float2v vp0 = (float2v){p0, p0};
            float2v vp1 = (float2v){p1, p1};
            float2v vp2 = (float2v){p2, p2};
            float2v vp3 = (float2v){p3, p3};
            #pragma unroll
            for (int q8 = 0; q8 < 8; ++q8) {
                acc2[q8]      = vp0 * ys2[q8] + acc2[q8];      // v_pk_fma_f32
                acc2[8  + q8] = vp1 * ys2[q8] + acc2[8  + q8];
                acc2[16 + q8] = vp2 * ys2[q8] + acc2[16 + q8];
                acc2[24 + q8] = vp3 * ys2[q8] + acc2[24 + q8];
            }
        }
    }

    // Wave-local reduction (each wave owns red[w] -> no barriers).
    // Pad-33 transpose: both phases are 2-way bank aliases = free (m136).
    __shared__ float red[4][64][33];      // ~33.8 KB
    const int col  = lane & 31;
    const int half = lane >> 5;
    #pragma unroll
    for (int ch = 0; ch < 2; ++ch) {
        #pragma unroll
        for (int q = 0; q < 32; ++q)
            red[w][lane][q] = acc2[(ch*32 + q) >> 1][q & 1];
        float csum = 0.0f;
        #pragma unroll
        for (int r = 0; r < 32; ++r)
            csum += red[w][half*32 + r][col];
        float other = __shfl_down(csum, 32);   // half 1 -> half 0
        if (lane < 32)
            ws[((atom*SLABS + slab)*4 + w)*64 + ch*32 + lane] = csum + other;
    }
}

// out[atom][n*16+q] = VCELL * sum_k W[n][k] * M[k][q]
// M[k][q] = sum over slab(16) x cw(2) of ws[((atom*16+s)*4 + (k>>2)*2+cw)*64
//                                          + (k&3)*16 + q]
__global__ void finalize_kernel(const float* __restrict__ ws,
                                const float* __restrict__ W,
                                float* __restrict__ out)
{
    const int atom = blockIdx.x;
    const int t = threadIdx.x;        // 128 threads
    const int n = t >> 4, q = t & 15;
    const int g = n >> 2, r = n & 3;
    const float* base = ws + atom*SLABS*4*64;
    float m = 0.0f;
    #pragma unroll
    for (int s = 0; s < SLABS; ++s) {
        m += base[(s*4 + g*2 + 0)*64 + r*16 + q];
        m += base[(s*4 + g*2 + 1)*64 + r*16 + q];
    }
    __shared__ float M[8][16];
    M[n][q] = m;
    __syncthreads();
    float sum = 0.0f;
    #pragma unroll
    for (int k = 0; k < 8; ++k)
        sum = fmaf(W[n*8+k], M[k][q], sum);
    out[atom*128 + t] = sum * VCELL_F;
}

extern "C" void kernel_launch(void* const* d_in, const int* in_sizes, int n_in,
                              void* d_out, int out_size, void* d_ws, size_t ws_size,
                              hipStream_t stream) {
    const float* rho = (const float*)d_in[0];   // 180^3
    const float* pos = (const float*)d_in[1];   // 64 x 3
    const float* W   = (const float*)d_in[2];   // 8 x 8
    float* out = (float*)d_out;                 // 64 x 128 fp32
    float* ws  = (float*)d_ws;                  // 64*16*4*64 fp32 partials

    dim3 grid(SLABS, NATOMS);
    proj_kernel<<<grid, 256, 0, stream>>>(rho, pos, ws);
    finalize_kernel<<<NATOMS, 128, 0, stream>>>(ws, W, out);
}